// Round 3
// baseline (228.927 us; speedup 1.0000x reference)
//
#include <hip/hip_runtime.h>
#include <math.h>

// ---------------------------------------------------------------------------
// EEGGENET fused implementation (round 3).
// Shapes: B=64, C=64, T=1000, F1=8, D=2, F2=16, KLEN=64, NCLS=4.
//
// Algebra: graph conv + spatial conv + BN1 + BN2 fold into Wf[48][64]; channel
// contraction commutes with the temporal conv:
//   s[b,oc,t] = sum_q tw[f(oc),q] * p[oc][t-32+q] + bias[oc],
//   p[oc][u]  = sum_j Wf[oc][j] x[b,j,u]
// Stage1 (1024 blocks, 4/CU): float4 mix (thread = col-quad x 6-oc group) ->
// LDS ps -> FIR(64)+ELU+pool8 -> out1. Last block per b (atomic counter) runs
// stage2 inline: dw conv -> pw -> BN3+ELU -> pool8 -> classifier.
// ---------------------------------------------------------------------------

#define EPS_BN 1e-3f

// ws layout (floats)
#define WF_OFF   0        // WfT[64][48]  (j-major, BN1*BN2 folded)
#define BIAS_OFF 3072     // bias[48]
#define A3_OFF   3120     // a3[16]
#define C3_OFF   3136     // c3[16]
#define CLS_OFF  3152     // renormed cls_w [4][240]
#define CNT_OFF  4112     // 64 uint counters
#define OUT1_OFF 4176     // pooled stage-1 output [64][48][125]

// stage1 smem layout (floats): total 9968 = 39872 B -> 4 blocks/CU
#define S_PS   0          // [48][132]
#define S_W    6336       // WfT[64][48]
#define S_TW   9408       // [8][64]
#define S_BIAS 9920       // [48]
#define S_TOT  9968
// stage2 overlay: DWO [48][126] @0, QQ [16][126] @6048

// ---------------------------------------------------------------------------
__global__ __launch_bounds__(256) void eeg_setup_kernel(
    const float* __restrict__ g1, const float* __restrict__ b1,
    const float* __restrict__ m1, const float* __restrict__ v1,
    const float* __restrict__ e1, const float* __restrict__ e2,
    const float* __restrict__ sw,
    const float* __restrict__ g2, const float* __restrict__ b2,
    const float* __restrict__ m2, const float* __restrict__ v2,
    const float* __restrict__ g3, const float* __restrict__ b3,
    const float* __restrict__ m3, const float* __restrict__ v3,
    const float* __restrict__ clsw, float* __restrict__ ws)
{
    const int tid = threadIdx.x;
    const int blk = blockIdx.x;

    if (blk < 48) {
        const int oc = blk;
        const int k = oc >> 4;          // hop: 0=identity, 1=A1, 2=A2
        __shared__ float A[64][65];
        __shared__ float rsl[64];
        __shared__ float swl[64];
        __shared__ float sred;

        if (k > 0) {
            const float* e = (k == 1) ? e1 : e2;
            for (int idx = tid; idx < 4096; idx += 256) {
                int i = idx >> 6, j = idx & 63;
                float v;
                if (i == j) v = 1.f;
                else {
                    int ii = i > j ? i : j, jj = i > j ? j : i;
                    v = e[ii * (ii - 1) / 2 + jj];
                }
                A[i][j] = v;
            }
        }
        if (tid < 64) swl[tid] = sw[oc * 64 + tid];
        __syncthreads();
        if (tid < 64) {
            if (k > 0) {
                float s = 0.f;
                for (int j = 0; j < 64; ++j) s += A[tid][j];
                rsl[tid] = 1.f / s;
            }
            float nv = swl[tid] * swl[tid];
            for (int off = 32; off; off >>= 1) nv += __shfl_down(nv, off);
            if (tid == 0) sred = nv;
        }
        __syncthreads();
        if (tid < 64) {
            const int j = tid;
            const float sn = fminf(1.f, 1.f / fmaxf(sqrtf(sred), 1e-7f));
            float w;
            if (k == 0) w = swl[j];
            else {
                float acc = 0.f;
                for (int c = 0; c < 64; ++c) acc += swl[c] * rsl[c] * A[c][j];
                w = acc;
            }
            w *= sn;
            const int f = (oc >> 1) & 7;
            const float a1 = g1[f] * rsqrtf(v1[f] + EPS_BN);
            const float a2 = g2[oc] * rsqrtf(v2[oc] + EPS_BN);
            ws[WF_OFF + j * 48 + oc] = a2 * a1 * w;
            float S = w;
            for (int off = 32; off; off >>= 1) S += __shfl_down(S, off);
            if (tid == 0) {
                const float c1 = b1[f] - m1[f] * a1;
                const float c2 = b2[oc] - m2[oc] * a2;
                ws[BIAS_OFF + oc] = a2 * c1 * S + c2;
            }
        }
    } else {
        __shared__ float csc[4];
        if (tid < 16) {
            const float a3 = g3[tid] * rsqrtf(v3[tid] + EPS_BN);
            ws[A3_OFF + tid] = a3;
            ws[C3_OFF + tid] = b3[tid] - m3[tid] * a3;
        }
        if (tid < 64) ((unsigned*)(ws + CNT_OFF))[tid] = 0u;   // per-b counters
        {   // classifier renorm (maxnorm 0.25): row = wave
            const int row = tid >> 6, lane = tid & 63;
            float p = 0.f;
            if (row < 4)
                for (int idx = lane; idx < 240; idx += 64) {
                    float w = clsw[row * 240 + idx];
                    p += w * w;
                }
            for (int off = 32; off; off >>= 1) p += __shfl_down(p, off);
            if (row < 4 && lane == 0)
                csc[row] = fminf(1.f, 0.25f / fmaxf(sqrtf(p), 1e-7f));
        }
        __syncthreads();
        for (int idx = tid; idx < 960; idx += 256)
            ws[CLS_OFF + idx] = clsw[idx] * csc[idx / 240];
    }
}

// ---------------------------------------------------------------------------
__global__ __launch_bounds__(256, 4) void eeg_stage1_kernel(
    const float* __restrict__ x, const float* __restrict__ tw,
    float* __restrict__ ws,
    const float* __restrict__ dww, const float* __restrict__ pww,
    const float* __restrict__ clsb, float* __restrict__ out)
{
    __shared__ float smem[S_TOT];
    __shared__ int do2;
    const int tid = threadIdx.x;
    // XCD-aware swizzle (1024 % 8 == 0, bijective): each XCD gets 8 full b's
    const int newid = (blockIdx.x & 7) * 128 + (blockIdx.x >> 3);
    const int b = newid >> 4;
    const int tile = newid & 15;
    const int o0 = tile * 8;
    const int no = (125 - o0) < 8 ? (125 - o0) : 8;   // 8, last tile 5
    const int u0 = 64 * tile - 32;

    {   // stage weights
        float4* wd = (float4*)(smem + S_W);
        const float4* wsrc = (const float4*)(ws + WF_OFF);
        for (int i = tid; i < 768; i += 256) wd[i] = wsrc[i];
        float4* td = (float4*)(smem + S_TW);
        const float4* tsrc = (const float4*)tw;
        for (int i = tid; i < 128; i += 256) td[i] = tsrc[i];
        if (tid < 48) smem[S_BIAS + tid] = ws[BIAS_OFF + tid];
    }
    __syncthreads();

    {   // channel mix: thread = (column quad, oc-group of 6)
        const int quad = tid & 31;          // ul = 4*quad
        const int g = tid >> 5;             // ocs g*6 .. g*6+5
        const int u = u0 + 4 * quad;
        const bool valid = (u >= 0) && (u + 3 < 1000);
        const float* xq = x + (size_t)b * 64000 + u;
        float4 acc[6];
#pragma unroll
        for (int c = 0; c < 6; ++c) acc[c] = make_float4(0.f, 0.f, 0.f, 0.f);
#pragma unroll 4
        for (int j = 0; j < 64; ++j) {
            float4 xv = valid ? *(const float4*)(xq + j * 1000)
                              : make_float4(0.f, 0.f, 0.f, 0.f);
            const float* wj = smem + S_W + j * 48 + g * 6;
            float2 wa = *(const float2*)(wj);
            float2 wb = *(const float2*)(wj + 2);
            float2 wc = *(const float2*)(wj + 4);
            float wv[6] = {wa.x, wa.y, wb.x, wb.y, wc.x, wc.y};
#pragma unroll
            for (int c = 0; c < 6; ++c) {
                acc[c].x += wv[c] * xv.x;
                acc[c].y += wv[c] * xv.y;
                acc[c].z += wv[c] * xv.z;
                acc[c].w += wv[c] * xv.w;
            }
        }
#pragma unroll
        for (int c = 0; c < 6; ++c)
            *(float4*)(smem + S_PS + (g * 6 + c) * 132 + 4 * quad) = acc[c];
    }
    __syncthreads();

    // FIR(64) + bias + ELU + pool8
    const int ntasks = 48 * no;
    for (int task = tid; task < ntasks; task += 256) {
        const int oc = task / no;
        const int o = task - oc * no;
        const int f = (oc >> 1) & 7;
        const float* row = smem + S_PS + oc * 132 + o * 8;
        const float bs = smem[S_BIAS + oc];
        float accv[8];
#pragma unroll
        for (int r = 0; r < 8; ++r) accv[r] = bs;
#pragma unroll
        for (int q0 = 0; q0 < 64; q0 += 8) {
            float win[16];
            const float4* pv = (const float4*)(row + q0);
#pragma unroll
            for (int gg = 0; gg < 4; ++gg) {
                float4 v = pv[gg];
                win[4 * gg + 0] = v.x; win[4 * gg + 1] = v.y;
                win[4 * gg + 2] = v.z; win[4 * gg + 3] = v.w;
            }
#pragma unroll
            for (int q = 0; q < 8; ++q) {
                float tv = smem[S_TW + f * 64 + q0 + q];
#pragma unroll
                for (int r = 0; r < 8; ++r) accv[r] += tv * win[q + r];
            }
        }
        float s = 0.f;
#pragma unroll
        for (int r = 0; r < 8; ++r) {
            float v = accv[r];
            s += (v > 0.f) ? v : expm1f(v);
        }
        ws[OUT1_OFF + ((size_t)b * 48 + oc) * 125 + (o0 + o)] = s * 0.125f;
    }

    // ---- completion count; last tile for this b runs stage2 inline ----
    __threadfence();          // release out1 stores device-wide
    __syncthreads();
    if (tid == 0) {
        unsigned* cnt = (unsigned*)(ws + CNT_OFF);
        unsigned prev = __hip_atomic_fetch_add(&cnt[b], 1u,
                          __ATOMIC_ACQ_REL, __HIP_MEMORY_SCOPE_AGENT);
        do2 = (prev == 15u) ? 1 : 0;
    }
    __syncthreads();
    if (!do2) return;
    __threadfence();          // acquire: see other blocks' out1

    const float* o1 = ws + OUT1_OFF + (size_t)b * 6000;
    float* dwo = smem;          // [48][126]  (clobbers PS/W: done with them)
    float* qq = smem + 6048;    // [16][126]

    // depthwise conv: K=16, pad 8, 125 -> 126  (o1 via L1)
    for (int idx = tid; idx < 48 * 126; idx += 256) {
        int ci = idx / 126, t = idx - ci * 126;
        float acc = 0.f;
#pragma unroll
        for (int r = 0; r < 16; ++r) {
            int tt = t - 8 + r;
            float xv = (tt >= 0 && tt < 125) ? o1[ci * 125 + tt] : 0.f;
            acc += dww[ci * 16 + r] * xv;
        }
        dwo[idx] = acc;
    }
    __syncthreads();
    // pointwise 48->16 + BN3 + ELU
    for (int idx = tid; idx < 16 * 126; idx += 256) {
        int co = idx / 126, t = idx - co * 126;
        float acc = 0.f;
#pragma unroll
        for (int ci = 0; ci < 48; ++ci)
            acc += pww[co * 48 + ci] * dwo[ci * 126 + t];
        float v = ws[A3_OFF + co] * acc + ws[C3_OFF + co];
        qq[idx] = (v > 0.f) ? v : expm1f(v);
    }
    __syncthreads();
    // pool8: uses t 0..119 -> 15 per co
    for (int idx = tid; idx < 240; idx += 256) {
        int co = idx / 15, v = idx - co * 15;
        float s = 0.f;
#pragma unroll
        for (int r = 0; r < 8; ++r) s += qq[co * 126 + v * 8 + r];
        dwo[idx] = s * 0.125f;
    }
    __syncthreads();
    // classifier: wave w -> class w, 64-lane reduce over 240
    {
        const int wv = tid >> 6, lane = tid & 63;
        float p = 0.f;
        for (int j2 = lane; j2 < 240; j2 += 64)
            p += ws[CLS_OFF + wv * 240 + j2] * dwo[j2];
        for (int off = 32; off; off >>= 1) p += __shfl_down(p, off);
        if (lane == 0) out[(size_t)b * 4 + wv] = p + clsb[wv];
    }
}

extern "C" void kernel_launch(void* const* d_in, const int* in_sizes, int n_in,
                              void* d_out, int out_size, void* d_ws, size_t ws_size,
                              hipStream_t stream) {
    const float* x    = (const float*)d_in[0];
    const float* tw   = (const float*)d_in[1];
    const float* g1   = (const float*)d_in[2];
    const float* b1   = (const float*)d_in[3];
    const float* m1   = (const float*)d_in[4];
    const float* v1   = (const float*)d_in[5];
    const float* e1   = (const float*)d_in[6];
    const float* e2   = (const float*)d_in[7];
    const float* sw   = (const float*)d_in[8];
    const float* g2   = (const float*)d_in[9];
    const float* b2   = (const float*)d_in[10];
    const float* m2   = (const float*)d_in[11];
    const float* v2   = (const float*)d_in[12];
    const float* dww  = (const float*)d_in[13];
    const float* pww  = (const float*)d_in[14];
    const float* g3   = (const float*)d_in[15];
    const float* b3   = (const float*)d_in[16];
    const float* v3g  = (const float*)d_in[17];
    const float* v3   = (const float*)d_in[18];
    const float* clsw = (const float*)d_in[19];
    const float* clsb = (const float*)d_in[20];
    float* ws = (float*)d_ws;
    float* out = (float*)d_out;

    eeg_setup_kernel<<<49, 256, 0, stream>>>(g1, b1, m1, v1, e1, e2, sw,
                                             g2, b2, m2, v2, g3, b3, v3g, v3,
                                             clsw, ws);
    eeg_stage1_kernel<<<1024, 256, 0, stream>>>(x, tw, ws, dww, pww, clsb, out);
}

// Round 4
// 75.435 us; speedup vs baseline: 3.0347x; 3.0347x over previous
//
#include <hip/hip_runtime.h>
#include <math.h>

// ---------------------------------------------------------------------------
// EEGGENET fused implementation (round 4).
// Shapes: B=64, C=64, T=1000, F1=8, D=2, F2=16, KLEN=64, NCLS=4.
//
// Algebra: graph conv + spatial conv + BN1 + BN2 fold into Wf[48][64]; channel
// contraction commutes with the temporal conv:
//   s[b,oc,t] = sum_q tw[f(oc),q] * p[oc][t-32+q] + bias[oc],
//   p[oc][u]  = sum_j Wf[oc][j] x[b,j,u]
// 3 kernels, NO cross-block atomics/fences (round-3 fence storm cost ~170us):
//   setup (49 blk) -> stage1 (1024 blk, mix+FIR+pool) -> stage2 (64 blk).
// ---------------------------------------------------------------------------

#define EPS_BN 1e-3f

// ws layout (floats)
#define WF_OFF   0        // WfT[64][48]  (j-major, BN1*BN2 folded)
#define BIAS_OFF 3072     // bias[48]
#define A3_OFF   3120     // a3[16]
#define C3_OFF   3136     // c3[16]
#define CLS_OFF  3152     // renormed cls_w [4][240]
#define OUT1_OFF 4176     // pooled stage-1 output [64][48][125]

// stage1 smem layout (floats): total 9968 = 39872 B -> 4 blocks/CU
#define S_PS   0          // [48][132]
#define S_W    6336       // WfT[64][48]
#define S_TW   9408       // [8][64]
#define S_BIAS 9920       // [48]
#define S_TOT  9968

// ---------------------------------------------------------------------------
__global__ __launch_bounds__(256) void eeg_setup_kernel(
    const float* __restrict__ g1, const float* __restrict__ b1,
    const float* __restrict__ m1, const float* __restrict__ v1,
    const float* __restrict__ e1, const float* __restrict__ e2,
    const float* __restrict__ sw,
    const float* __restrict__ g2, const float* __restrict__ b2,
    const float* __restrict__ m2, const float* __restrict__ v2,
    const float* __restrict__ g3, const float* __restrict__ b3,
    const float* __restrict__ m3, const float* __restrict__ v3,
    const float* __restrict__ clsw, float* __restrict__ ws)
{
    const int tid = threadIdx.x;
    const int blk = blockIdx.x;

    if (blk < 48) {
        const int oc = blk;
        const int k = oc >> 4;          // hop: 0=identity, 1=A1, 2=A2
        __shared__ float A[64][65];
        __shared__ float rsl[64];
        __shared__ float swl[64];
        __shared__ float sred;

        if (k > 0) {
            const float* e = (k == 1) ? e1 : e2;
            for (int idx = tid; idx < 4096; idx += 256) {
                int i = idx >> 6, j = idx & 63;
                float v;
                if (i == j) v = 1.f;
                else {
                    int ii = i > j ? i : j, jj = i > j ? j : i;
                    v = e[ii * (ii - 1) / 2 + jj];
                }
                A[i][j] = v;
            }
        }
        if (tid < 64) swl[tid] = sw[oc * 64 + tid];
        __syncthreads();
        if (tid < 64) {
            if (k > 0) {
                float s = 0.f;
                for (int j = 0; j < 64; ++j) s += A[tid][j];
                rsl[tid] = 1.f / s;
            }
            float nv = swl[tid] * swl[tid];
            for (int off = 32; off; off >>= 1) nv += __shfl_down(nv, off);
            if (tid == 0) sred = nv;
        }
        __syncthreads();
        if (tid < 64) {
            const int j = tid;
            const float sn = fminf(1.f, 1.f / fmaxf(sqrtf(sred), 1e-7f));
            float w;
            if (k == 0) w = swl[j];
            else {
                float acc = 0.f;
                for (int c = 0; c < 64; ++c) acc += swl[c] * rsl[c] * A[c][j];
                w = acc;
            }
            w *= sn;
            const int f = (oc >> 1) & 7;
            const float a1 = g1[f] * rsqrtf(v1[f] + EPS_BN);
            const float a2 = g2[oc] * rsqrtf(v2[oc] + EPS_BN);
            ws[WF_OFF + j * 48 + oc] = a2 * a1 * w;
            float S = w;
            for (int off = 32; off; off >>= 1) S += __shfl_down(S, off);
            if (tid == 0) {
                const float c1 = b1[f] - m1[f] * a1;
                const float c2 = b2[oc] - m2[oc] * a2;
                ws[BIAS_OFF + oc] = a2 * c1 * S + c2;
            }
        }
    } else {
        __shared__ float csc[4];
        if (tid < 16) {
            const float a3 = g3[tid] * rsqrtf(v3[tid] + EPS_BN);
            ws[A3_OFF + tid] = a3;
            ws[C3_OFF + tid] = b3[tid] - m3[tid] * a3;
        }
        {   // classifier renorm (maxnorm 0.25): row = wave
            const int row = tid >> 6, lane = tid & 63;
            float p = 0.f;
            if (row < 4)
                for (int idx = lane; idx < 240; idx += 64) {
                    float w = clsw[row * 240 + idx];
                    p += w * w;
                }
            for (int off = 32; off; off >>= 1) p += __shfl_down(p, off);
            if (row < 4 && lane == 0)
                csc[row] = fminf(1.f, 0.25f / fmaxf(sqrtf(p), 1e-7f));
        }
        __syncthreads();
        for (int idx = tid; idx < 960; idx += 256)
            ws[CLS_OFF + idx] = clsw[idx] * csc[idx / 240];
    }
}

// ---------------------------------------------------------------------------
// Stage 1: per (b, tile of 8 pool outputs) = 1024 blocks, 4 blocks/CU.
// Mix: thread = (col-quad, 6-oc group), j-loop unrolled x8 with 8 float4
// loads hoisted (128 B/thread in flight). Then FIR(64)+bias+ELU+pool8.
// ---------------------------------------------------------------------------
__global__ __launch_bounds__(256, 4) void eeg_stage1_kernel(
    const float* __restrict__ x, const float* __restrict__ tw,
    const float* __restrict__ wcon, float* __restrict__ out1)
{
    __shared__ float smem[S_TOT];
    const int tid = threadIdx.x;
    // XCD-aware swizzle (1024 % 8 == 0, bijective): each XCD gets 8 full b's
    const int newid = (blockIdx.x & 7) * 128 + (blockIdx.x >> 3);
    const int b = newid >> 4;
    const int tile = newid & 15;
    const int o0 = tile * 8;
    const int no = (125 - o0) < 8 ? (125 - o0) : 8;   // 8, last tile 5
    const int u0 = 64 * tile - 32;

    {   // stage weights
        float4* wd = (float4*)(smem + S_W);
        const float4* wsrc = (const float4*)(wcon + WF_OFF);
        for (int i = tid; i < 768; i += 256) wd[i] = wsrc[i];
        float4* td = (float4*)(smem + S_TW);
        const float4* tsrc = (const float4*)tw;
        for (int i = tid; i < 128; i += 256) td[i] = tsrc[i];
        if (tid < 48) smem[S_BIAS + tid] = wcon[BIAS_OFF + tid];
    }
    __syncthreads();

    {   // channel mix: thread = (column quad, oc-group of 6)
        const int quad = tid & 31;          // ul = 4*quad
        const int g = tid >> 5;             // ocs g*6 .. g*6+5
        const int u = u0 + 4 * quad;
        const bool valid = (u >= 0) && (u + 3 < 1000);
        const float* xq = x + (size_t)b * 64000 + u;
        float4 acc[6];
#pragma unroll
        for (int c = 0; c < 6; ++c) acc[c] = make_float4(0.f, 0.f, 0.f, 0.f);
        for (int j0 = 0; j0 < 64; j0 += 8) {
            float4 xv[8];
#pragma unroll
            for (int jj = 0; jj < 8; ++jj)
                xv[jj] = valid ? *(const float4*)(xq + (j0 + jj) * 1000)
                               : make_float4(0.f, 0.f, 0.f, 0.f);
#pragma unroll
            for (int jj = 0; jj < 8; ++jj) {
                const float* wj = smem + S_W + (j0 + jj) * 48 + g * 6;
                float2 wa = *(const float2*)(wj);
                float2 wb = *(const float2*)(wj + 2);
                float2 wc = *(const float2*)(wj + 4);
                float wv[6] = {wa.x, wa.y, wb.x, wb.y, wc.x, wc.y};
#pragma unroll
                for (int c = 0; c < 6; ++c) {
                    acc[c].x += wv[c] * xv[jj].x;
                    acc[c].y += wv[c] * xv[jj].y;
                    acc[c].z += wv[c] * xv[jj].z;
                    acc[c].w += wv[c] * xv[jj].w;
                }
            }
        }
#pragma unroll
        for (int c = 0; c < 6; ++c)
            *(float4*)(smem + S_PS + (g * 6 + c) * 132 + 4 * quad) = acc[c];
    }
    __syncthreads();

    // FIR(64) + bias + ELU + pool8
    const int ntasks = 48 * no;
    for (int task = tid; task < ntasks; task += 256) {
        const int oc = task / no;
        const int o = task - oc * no;
        const int f = (oc >> 1) & 7;
        const float* row = smem + S_PS + oc * 132 + o * 8;
        const float bs = smem[S_BIAS + oc];
        float accv[8];
#pragma unroll
        for (int r = 0; r < 8; ++r) accv[r] = bs;
#pragma unroll
        for (int q0 = 0; q0 < 64; q0 += 8) {
            float win[16];
            const float4* pv = (const float4*)(row + q0);
#pragma unroll
            for (int gg = 0; gg < 4; ++gg) {
                float4 v = pv[gg];
                win[4 * gg + 0] = v.x; win[4 * gg + 1] = v.y;
                win[4 * gg + 2] = v.z; win[4 * gg + 3] = v.w;
            }
#pragma unroll
            for (int q = 0; q < 8; ++q) {
                float tv = smem[S_TW + f * 64 + q0 + q];
#pragma unroll
                for (int r = 0; r < 8; ++r) accv[r] += tv * win[q + r];
            }
        }
        float s = 0.f;
#pragma unroll
        for (int r = 0; r < 8; ++r) {
            float v = accv[r];
            s += (v > 0.f) ? v : expm1f(v);
        }
        out1[((size_t)b * 48 + oc) * 125 + (o0 + o)] = s * 0.125f;
    }
}

// ---------------------------------------------------------------------------
// Stage 2: per batch. dw conv(16,pad8) -> pw 48->16 -> BN3+ELU -> pool8 ->
// classifier. 64 blocks, float4 LDS staging.
// ---------------------------------------------------------------------------
#define SB_P1   0        // [48][125]  (reused for QQ [16][126])
#define SB_DWO  6000     // [48][126]  (reused for pooled [16][15])
#define SB_DWL  12048    // [48][16]
#define SB_PWL  12816    // [16][48]
#define SB_CLS  13584    // [4][240]
#define SB_A3   14544    // [16]
#define SB_C3   14560    // [16]
#define SB_TOT  14576

__global__ __launch_bounds__(256) void eeg_stage2_kernel(
    const float* __restrict__ ws, const float* __restrict__ dww,
    const float* __restrict__ pww, const float* __restrict__ clsb,
    float* __restrict__ out)
{
    __shared__ float sb[SB_TOT];
    const int tid = threadIdx.x;
    const int b = blockIdx.x;
    const float* o1 = ws + OUT1_OFF + (size_t)b * 6000;

    for (int i = tid; i < 1500; i += 256)
        ((float4*)(sb + SB_P1))[i] = ((const float4*)o1)[i];
    for (int i = tid; i < 192; i += 256)
        ((float4*)(sb + SB_DWL))[i] = ((const float4*)dww)[i];
    for (int i = tid; i < 192; i += 256)
        ((float4*)(sb + SB_PWL))[i] = ((const float4*)pww)[i];
    for (int i = tid; i < 240; i += 256)
        ((float4*)(sb + SB_CLS))[i] = ((const float4*)(ws + CLS_OFF))[i];
    if (tid < 16) { sb[SB_A3 + tid] = ws[A3_OFF + tid]; sb[SB_C3 + tid] = ws[C3_OFF + tid]; }
    __syncthreads();

    // depthwise conv: K=16, pad 8, T 125 -> 126
    for (int idx = tid; idx < 48 * 126; idx += 256) {
        int ci = idx / 126, t = idx - ci * 126;
        float acc = 0.f;
#pragma unroll
        for (int r = 0; r < 16; ++r) {
            int tt = t - 8 + r;
            float xv = (tt >= 0 && tt < 125) ? sb[SB_P1 + ci * 125 + tt] : 0.f;
            acc += sb[SB_DWL + ci * 16 + r] * xv;
        }
        sb[SB_DWO + idx] = acc;
    }
    __syncthreads();
    // pointwise 48->16 + BN3 + ELU  (overwrites P1 region, disjoint from DWO)
    for (int idx = tid; idx < 16 * 126; idx += 256) {
        int co = idx / 126, t = idx - co * 126;
        float acc = 0.f;
#pragma unroll
        for (int ci = 0; ci < 48; ++ci)
            acc += sb[SB_PWL + co * 48 + ci] * sb[SB_DWO + ci * 126 + t];
        float v = sb[SB_A3 + co] * acc + sb[SB_C3 + co];
        sb[SB_P1 + idx] = (v > 0.f) ? v : expm1f(v);
    }
    __syncthreads();
    // pool8: 126 -> 15 (overwrites DWO region)
    for (int idx = tid; idx < 240; idx += 256) {
        int co = idx / 15, v = idx - co * 15;
        float s = 0.f;
#pragma unroll
        for (int r = 0; r < 8; ++r) s += sb[SB_P1 + co * 126 + v * 8 + r];
        sb[SB_DWO + idx] = s * 0.125f;
    }
    __syncthreads();
    // classifier: wave w -> class w, 64-lane reduce over 240
    {
        const int wv = tid >> 6, lane = tid & 63;
        float p = 0.f;
        for (int j2 = lane; j2 < 240; j2 += 64)
            p += sb[SB_CLS + wv * 240 + j2] * sb[SB_DWO + j2];
        for (int off = 32; off; off >>= 1) p += __shfl_down(p, off);
        if (lane == 0) out[(size_t)b * 4 + wv] = p + clsb[wv];
    }
}

extern "C" void kernel_launch(void* const* d_in, const int* in_sizes, int n_in,
                              void* d_out, int out_size, void* d_ws, size_t ws_size,
                              hipStream_t stream) {
    const float* x    = (const float*)d_in[0];
    const float* tw   = (const float*)d_in[1];
    const float* g1   = (const float*)d_in[2];
    const float* b1   = (const float*)d_in[3];
    const float* m1   = (const float*)d_in[4];
    const float* v1   = (const float*)d_in[5];
    const float* e1   = (const float*)d_in[6];
    const float* e2   = (const float*)d_in[7];
    const float* sw   = (const float*)d_in[8];
    const float* g2   = (const float*)d_in[9];
    const float* b2   = (const float*)d_in[10];
    const float* m2   = (const float*)d_in[11];
    const float* v2   = (const float*)d_in[12];
    const float* dww  = (const float*)d_in[13];
    const float* pww  = (const float*)d_in[14];
    const float* g3   = (const float*)d_in[15];
    const float* b3   = (const float*)d_in[16];
    const float* m3   = (const float*)d_in[17];
    const float* v3   = (const float*)d_in[18];
    const float* clsw = (const float*)d_in[19];
    const float* clsb = (const float*)d_in[20];
    float* ws = (float*)d_ws;
    float* out = (float*)d_out;

    eeg_setup_kernel<<<49, 256, 0, stream>>>(g1, b1, m1, v1, e1, e2, sw,
                                             g2, b2, m2, v2, g3, b3, m3, v3,
                                             clsw, ws);
    eeg_stage1_kernel<<<1024, 256, 0, stream>>>(x, tw, ws, ws + OUT1_OFF);
    eeg_stage2_kernel<<<64, 256, 0, stream>>>(ws, dww, pww, clsb, out);
}